// Round 20
// baseline (639.206 us; speedup 1.0000x reference)
//
#include <hip/hip_runtime.h>
#include <hip/hip_fp16.h>
#include <math.h>

#define NREP 16
#define RDIM 16
#define NS   16
#define NC   6
#define H1   144
#define DBINS 64

static __device__ __forceinline__ float leaky(float v) { return v > 0.0f ? v : 0.01f * v; }

typedef float nf4 __attribute__((ext_vector_type(4)));
static __device__ __forceinline__ float4 ntload4(const float4* p) {
  nf4 v = __builtin_nontemporal_load((const nf4*)p);
  return make_float4(v.x, v.y, v.z, v.w);
}
static __device__ __forceinline__ void ntstore4(float4* p, float4 v) {
  nf4 w = {v.x, v.y, v.z, v.w};
  __builtin_nontemporal_store(w, (nf4*)p);
}

// ---------- fused: per-graph mean (LDS-binned) + edge row count ----------
__global__ void k_gsum_count(const float* __restrict__ pos, const int* __restrict__ batch,
                             int N, float* __restrict__ gsum, float* __restrict__ gcnt,
                             const int* __restrict__ ei, int E, int* __restrict__ cnt) {
  int t = threadIdx.x;
  int e = blockIdx.x * 256 + t;
  if (e < E) atomicAdd(&cnt[ei[e]], 1);

  __shared__ float bx[320], by[320], bc[320];
  int start = blockIdx.x * 256;
  if (start >= N) return;
  int n = start + t;
  int b0 = batch[min(start, N - 1)];
  int span = batch[min(start + 255, N - 1)] - b0;
  bool useLds = (span < 320);
  if (useLds) {
    for (int i = t; i <= span; i += 256) { bx[i] = 0.f; by[i] = 0.f; bc[i] = 0.f; }
    __syncthreads();
    if (n < N) {
      int rb = batch[n] - b0;
      atomicAdd(&bx[rb], pos[2 * n + 0]);
      atomicAdd(&by[rb], pos[2 * n + 1]);
      atomicAdd(&bc[rb], 1.0f);
    }
    __syncthreads();
    for (int i = t; i <= span; i += 256) {
      if (bc[i] != 0.0f) {
        atomicAdd(&gsum[2 * (b0 + i) + 0], bx[i]);
        atomicAdd(&gsum[2 * (b0 + i) + 1], by[i]);
        atomicAdd(&gcnt[b0 + i], bc[i]);
      }
    }
  } else if (n < N) {
    int b = batch[n];
    atomicAdd(&gsum[2 * b + 0], pos[2 * n + 0]);
    atomicAdd(&gsum[2 * b + 1], pos[2 * n + 1]);
    atomicAdd(&gcnt[b], 1.0f);
  }
}

// ---------- fused: center + degree histogram + scan phase 1 ----------
__global__ void k_center_dhist_scan1(
    const float* __restrict__ pos, const int* __restrict__ batch, int N,
    const float* __restrict__ gsum, const float* __restrict__ gcnt,
    float* __restrict__ posc, float* __restrict__ cthn, float* __restrict__ sthn,
    const int* __restrict__ cnt, int* __restrict__ dhist,
    int* __restrict__ off, int* __restrict__ bsum) {
  __shared__ int lh[DBINS];
  __shared__ int sd[1024];
  int t = threadIdx.x;
  int i = blockIdx.x * 1024 + t;
  if (t < DBINS) lh[t] = 0;
  int v = (i < N) ? cnt[i] : 0;
  sd[t] = v;
  if (i < N) {
    int b = batch[i];
    float invc = 1.0f / fmaxf(gcnt[b], 1.0f);
    float px = pos[2 * i + 0] - gsum[2 * b + 0] * invc;
    float py = pos[2 * i + 1] - gsum[2 * b + 1] * invc;
    posc[2 * i + 0] = px;
    posc[2 * i + 1] = py;
    float r = sqrtf(px * px + py * py);
    if (r > 0.0f) { cthn[i] = px / r; sthn[i] = py / r; }
    else          { cthn[i] = 1.0f;  sthn[i] = 0.0f; }
  }
  __syncthreads();
  if (i < N) atomicAdd(&lh[min(v, DBINS - 1)], 1);
  for (int o = 1; o < 1024; o <<= 1) {
    int u = (t >= o) ? sd[t - o] : 0;
    __syncthreads();
    sd[t] += u;
    __syncthreads();
  }
  if (i < N) off[i] = sd[t] - v;
  if (t == 1023) bsum[blockIdx.x] = sd[1023];
  if (t < DBINS && lh[t] > 0) atomicAdd(&dhist[t], lh[t]);
}

// ---------- fused: degree-bin exclusive scan + block-sum exclusive scan ----------
__global__ void k_dscan_scan2(const int* __restrict__ dhist, int* __restrict__ dcur,
                              int* __restrict__ bsum, int nb) {
  __shared__ int s1[DBINS];
  __shared__ int s2[1024];
  int t = threadIdx.x;
  int v1 = (t < DBINS) ? dhist[t] : 0;
  if (t < DBINS) s1[t] = v1;
  int v2 = (t < nb) ? bsum[t] : 0;
  s2[t] = v2;
  __syncthreads();
  for (int o = 1; o < 1024; o <<= 1) {
    int u1 = (o < DBINS && t >= o && t < DBINS) ? s1[t - o] : 0;
    int u2 = (t >= o) ? s2[t - o] : 0;
    __syncthreads();
    if (o < DBINS && t < DBINS) s1[t] += u1;
    s2[t] += u2;
    __syncthreads();
  }
  if (t < DBINS) dcur[t] = s1[t] - v1;
  if (t < nb) bsum[t] = s2[t] - v2;
}

// ---------- fused: scan phase 3 + degree-sort fill + cursor=off init ----------
__global__ void k_dfill_scan3(int* __restrict__ off, const int* __restrict__ bsum,
                              int N, int E,
                              const int* __restrict__ cnt, int* __restrict__ dcur,
                              int* __restrict__ perm, int* __restrict__ cursor) {
  int t = threadIdx.x;
  int i = blockIdx.x * 1024 + t;
  if (i < N) {
    int ov = off[i] + bsum[blockIdx.x];
    off[i] = ov;
    cursor[i] = ov;                     // k_build slots start at off[i]
  }
  if (i == N) off[N] = E;

  __shared__ int lh[DBINS];
  __shared__ int base[DBINS];
  if (t < DBINS) lh[t] = 0;
  __syncthreads();
  int b = 0, lr = 0;
  if (i < N) {
    b = min(cnt[i], DBINS - 1);
    lr = atomicAdd(&lh[b], 1);
  }
  __syncthreads();
  if (t < DBINS && lh[t] > 0) base[t] = atomicAdd(&dcur[t], lh[t]);
  __syncthreads();
  if (i < N) perm[base[b] + lr] = i;
}

// csr[k] = (sp' = sqrt2*sin(pi d)/(d+eps), c2 = 2*cos(pi d), col-bits, d)
// Single-pass scatter (~1 line-writeback per store — structural floor); nontemporal
// store keeps the dead payload out of L2.
__global__ void k_build(const float* __restrict__ posc, const int* __restrict__ ei, int E,
                        int* __restrict__ cursor, float4* __restrict__ csr) {
  int e = blockIdx.x * blockDim.x + threadIdx.x;
  if (e >= E) return;
  int r = ei[e], cl = ei[E + e];
  float dx = posc[2 * r + 0] - posc[2 * cl + 0];
  float dy = posc[2 * r + 1] - posc[2 * cl + 1];
  float d = sqrtf(dx * dx + dy * dy);
  float sp, cp;
  sincospif(d, &sp, &cp);
  float spp = 1.41421356237309515f * sp / (d + 1e-8f);
  int p = atomicAdd(&cursor[r], 1);
  ntstore4(&csr[p], make_float4(spp, 2.0f * cp, __int_as_float(cl), d));
}

// ---------- fused node init + layer-0 pre: 16 lanes/node, unified uint2 yzg ----------
__global__ void __launch_bounds__(256) k_init16(
    int N, const int* __restrict__ off, const float4* __restrict__ csr,
    const float* __restrict__ posc,
    const float* __restrict__ Wer, const float* __restrict__ wse, const float* __restrict__ bse,
    const float* __restrict__ Wmix, const float* __restrict__ Ws1, const float* __restrict__ bs1,
    const float* __restrict__ Wgate, const float* __restrict__ bgate,
    float* __restrict__ xr, float* __restrict__ xs, uint2* __restrict__ yzg) {
  int idx = blockIdx.x * 256 + threadIdx.x;
  int n = idx >> 4, r = idx & 15;
  if (n >= N) return;
  int a = off[n], b = off[n + 1];
  float px = posc[2 * n + 0], py = posc[2 * n + 1];
  float C = 0.f, S = 0.f, D = 0.f;
  for (int k = a + r; k < b; k += 16) {      // lane r: coalesced 256B group reads
    float4 v = ntload4(&csr[k]);             // stream — keep out of L2
    int cl = __float_as_int(v.z);
    float d = v.w;
    if (d > 0.0f) {
      float inv = 1.0f / d;
      C += (px - posc[2 * cl + 0]) * inv;
      S += (py - posc[2 * cl + 1]) * inv;
    } else {
      C += 1.0f;
    }
    D += d;
  }
#pragma unroll
  for (int o = 1; o < 16; o <<= 1) {         // butterfly: all 16 lanes get full sums
    C += __shfl_xor(C, o, 16);
    S += __shfl_xor(S, o, 16);
    D += __shfl_xor(D, o, 16);
  }
  float id = 1.0f / fmaxf((float)(b - a), 1.0f);
  C *= id; S *= id;
  float dm = D * id;
  float w0 = Wer[2 * r], w1 = Wer[2 * r + 1];
  float2 x;
  x.x = C * w0 - S * w1;
  x.y = S * w0 + C * w1;
  ((float2*)xr)[(size_t)n * 16 + r] = x;
  float s_new = leaky(dm * wse[r] + bse[r]);
  xs[(size_t)n * 16 + r] = s_new;

  // fused layer-0 pre (shuffle form — same pattern as k_layer's write_next tail)
  float wmxn[16], wsan[16], wgtn[16];
#pragma unroll
  for (int q = 0; q < 16; q++) wmxn[q] = Wmix[r * 16 + q];
#pragma unroll
  for (int q = 0; q < 16; q++) wsan[q] = Ws1[q * 16 + r];
#pragma unroll
  for (int q = 0; q < 16; q++) wgtn[q] = Wgate[q * 16 + r];
  float y0 = 0.f, y1 = 0.f;
  float z = bs1[r], gtn = bgate[r];
#pragma unroll
  for (int j = 0; j < 16; j++) {
    float xj0 = __shfl(x.x, j, 16);
    float xj1 = __shfl(x.y, j, 16);
    float sj  = __shfl(s_new, j, 16);
    y0 += wmxn[j] * xj0;
    y1 += wmxn[j] * xj1;
    z  += wsan[j] * sj;
    gtn += wgtn[j] * sj;
  }
  gtn = 1.0f / (1.0f + __expf(-gtn));
  __half2 hA = __floats2half2_rn(y0, y1);
  __half2 hB = __floats2half2_rn(z, gtn);
  uint2 w2;
  w2.x = *(unsigned int*)&hA;
  w2.y = *(unsigned int*)&hB;
  yzg[(size_t)n * 16 + r] = w2;
}

// ---------- EqBlock layer + fused next-layer pre (shuffle form, yzg ping-pong) ----------
__global__ void __launch_bounds__(256) k_layer(
    int N, const int* __restrict__ off, const float4* __restrict__ csr,
    const uint2* __restrict__ yzg, const int* __restrict__ perm,
    const float* __restrict__ Wg, const float* __restrict__ bg,
    const float* __restrict__ Ws1,   // this layer; demb rows are 16..31
    float* xr, float* xs,
    int write_next, uint2* __restrict__ yzg_out,
    const float* __restrict__ Wmixn, const float* __restrict__ Ws1n,
    const float* __restrict__ bs1n,
    const float* __restrict__ Wgaten, const float* __restrict__ bgaten) {
  int idx = blockIdx.x * 256 + threadIdx.x;
  int g = idx >> 4, r = idx & 15;
  if (g >= N) return;
  int n = perm[g];                      // degree-sorted: waves get equal-degree nodes
  float wg[16], ws[16];
#pragma unroll
  for (int q = 0; q < 16; q++) wg[q] = Wg[q * 16 + r];
#pragma unroll
  for (int q = 0; q < 16; q++) ws[q] = Ws1[(16 + q) * 16 + r];
  float bgr = bg[r];

  int a = off[n], bnd = off[n + 1];
  float acc0 = 0.f, acc1 = 0.f, accs = 0.f;
  if (a < bnd) {
    int last = bnd - 1;
    float4 v0 = ntload4(&csr[a]);
    float4 v1 = ntload4(&csr[min(a + 1, last)]);
    float4 v2 = ntload4(&csr[min(a + 2, last)]);
    uint2 Y0 = yzg[(size_t)__float_as_int(v0.z) * 16 + r];
    uint2 Y1 = yzg[(size_t)__float_as_int(v1.z) * 16 + r];
    for (int k = a; k < bnd; k++) {
      float4 v3 = ntload4(&csr[min(k + 3, last)]);   // stream — keep L2 for yzg
      uint2 Y2 = yzg[(size_t)__float_as_int(v2.z) * 16 + r];
      float skm1 = 0.f, sk = v0.x, c2 = v0.y;
      float g1 = bgr, dot = 0.f;
#pragma unroll
      for (int q = 0; q < RDIM; q++) {
        g1  = __builtin_fmaf(sk, wg[q], g1);
        dot = __builtin_fmaf(sk, ws[q], dot);
        float sn = __builtin_fmaf(c2, sk, -skm1);
        skm1 = sk; sk = sn;
      }
      float2 f01 = __half22float2(*(__half2*)&Y0.x);
      float2 fzg = __half22float2(*(__half2*)&Y0.y);
      acc0 = __builtin_fmaf(g1, f01.x, acc0);
      acc1 = __builtin_fmaf(g1, f01.y, acc1);
      accs += leaky(dot + fzg.x);
      v0 = v1; v1 = v2; v2 = v3; Y0 = Y1; Y1 = Y2;
    }
  }
  float id = 1.0f / fmaxf((float)(bnd - a), 1.0f);
  uint2 Yg = yzg[(size_t)n * 16 + r];
  float gt = __half22float2(*(__half2*)&Yg.y).y;
  float2* xr2 = (float2*)xr;
  float2 x = xr2[(size_t)n * 16 + r];
  x.x += acc0 * id * gt;
  x.y += acc1 * id * gt;
  xr2[(size_t)n * 16 + r] = x;            // in-place safe: (n,r) written only by this thread
  float s_new = xs[(size_t)n * 16 + r] + accs * id;
  xs[(size_t)n * 16 + r] = s_new;

  if (write_next) {
    // fused k_pre for next layer: cross-r via 16-wide shuffles (same sum order as k_pre)
    float wmxn[16], wsan[16], wgtn[16];
#pragma unroll
    for (int q = 0; q < 16; q++) wmxn[q] = Wmixn[r * 16 + q];
#pragma unroll
    for (int q = 0; q < 16; q++) wsan[q] = Ws1n[q * 16 + r];
#pragma unroll
    for (int q = 0; q < 16; q++) wgtn[q] = Wgaten[q * 16 + r];
    float y0 = 0.f, y1 = 0.f;
    float z = bs1n[r], gtn = bgaten[r];
#pragma unroll
    for (int j = 0; j < 16; j++) {
      float xj0 = __shfl(x.x, j, 16);
      float xj1 = __shfl(x.y, j, 16);
      float sj  = __shfl(s_new, j, 16);
      y0 += wmxn[j] * xj0;
      y1 += wmxn[j] * xj1;
      z  += wsan[j] * sj;
      gtn += wgtn[j] * sj;
    }
    gtn = 1.0f / (1.0f + __expf(-gtn));
    __half2 hA = __floats2half2_rn(y0, y1);
    __half2 hB = __floats2half2_rn(z, gtn);
    uint2 w2;
    w2.x = *(unsigned int*)&hA;
    w2.y = *(unsigned int*)&hB;
    yzg_out[(size_t)n * 16 + r] = w2;
  }
}

// ---------- final rotate-out + MLP (W1^T in LDS, 2-h ILP) + binned graph sum ----------
__global__ void __launch_bounds__(128) k_final(
    int N, const float* __restrict__ xr, const float* __restrict__ xs,
    const float* __restrict__ cthn, const float* __restrict__ sthn,
    const int* __restrict__ batch,
    const float* __restrict__ W1, const float* __restrict__ b1,
    const float* __restrict__ W2, const float* __restrict__ b2,
    float* __restrict__ out) {
  __shared__ float W1t[48 * H1];
  __shared__ float W2s[H1 * 6];
  __shared__ float b1s[H1];
  __shared__ float obin[320 * 6];
  int t = threadIdx.x;
  for (int i = t; i < 48 * H1; i += 128) { int q = i / H1, h = i - q * H1; W1t[h * 48 + q] = W1[i]; }
  for (int i = t; i < H1 * 6; i += 128) W2s[i] = W2[i];
  for (int i = t; i < H1; i += 128) b1s[i] = b1[i];

  int start = blockIdx.x * 128;
  int n = start + t;
  int b0 = batch[min(start, N - 1)];
  int span = batch[min(start + 127, N - 1)] - b0;
  bool useLds = (span < 320);
  if (useLds) for (int i = t; i < (span + 1) * 6; i += 128) obin[i] = 0.f;
  __syncthreads();

  float u[NC];
  bool act = (n < N);
  if (act) {
    float4 xcv[12];
    const float4* xs4 = (const float4*)(xs + (size_t)n * NS);
#pragma unroll
    for (int j = 0; j < 4; j++) xcv[j] = xs4[j];
    float c = cthn[n], s = sthn[n];
    const float4* xr4 = (const float4*)(xr + (size_t)n * 32);
#pragma unroll
    for (int j = 0; j < 8; j++) {
      float4 v = xr4[j];
      xcv[4 + j] = make_float4(c * v.x - s * v.y, s * v.x + c * v.y,
                               c * v.z - s * v.w, s * v.z + c * v.w);
    }
#pragma unroll
    for (int q = 0; q < NC; q++) u[q] = b2[q];
    for (int h = 0; h < H1; h += 2) {
      const float4* w0 = (const float4*)&W1t[h * 48];
      const float4* w1 = (const float4*)&W1t[(h + 1) * 48];
      float4 a0 = make_float4(0.f, 0.f, 0.f, 0.f);
      float4 a1 = make_float4(0.f, 0.f, 0.f, 0.f);
#pragma unroll
      for (int j = 0; j < 12; j++) {
        float4 x = xcv[j];
        float4 w = w0[j];
        a0.x += x.x * w.x; a0.y += x.y * w.y; a0.z += x.z * w.z; a0.w += x.w * w.w;
        float4 v = w1[j];
        a1.x += x.x * v.x; a1.y += x.y * v.y; a1.z += x.z * v.z; a1.w += x.w * v.w;
      }
      float aa0 = leaky((a0.x + a0.y) + (a0.z + a0.w) + b1s[h]);
      float aa1 = leaky((a1.x + a1.y) + (a1.z + a1.w) + b1s[h + 1]);
#pragma unroll
      for (int q = 0; q < NC; q++)
        u[q] += aa0 * W2s[h * 6 + q] + aa1 * W2s[(h + 1) * 6 + q];
    }
  }
  if (useLds) {
    if (act) {
      int rb = batch[n] - b0;
#pragma unroll
      for (int q = 0; q < NC; q++) atomicAdd(&obin[rb * 6 + q], u[q]);
    }
    __syncthreads();
    for (int i = t; i < (span + 1) * 6; i += 128) atomicAdd(&out[b0 * 6 + i], obin[i]);
  } else if (act) {
    int b = batch[n];
#pragma unroll
    for (int q = 0; q < NC; q++) atomicAdd(&out[b * 6 + q], u[q]);
  }
}

extern "C" void kernel_launch(void* const* d_in, const int* in_sizes, int n_in,
                              void* d_out, int out_size, void* d_ws, size_t ws_size,
                              hipStream_t stream) {
  const float* pos   = (const float*)d_in[0];
  const float* Wer   = (const float*)d_in[1];
  const float* wse   = (const float*)d_in[2];
  const float* bse   = (const float*)d_in[3];
  const float* Wg    = (const float*)d_in[4];
  const float* bg    = (const float*)d_in[5];
  const float* Wmix  = (const float*)d_in[6];
  const float* Wgate = (const float*)d_in[7];
  const float* bgate = (const float*)d_in[8];
  const float* Ws1   = (const float*)d_in[9];
  const float* bs1   = (const float*)d_in[10];
  const float* W1    = (const float*)d_in[11];
  const float* b1    = (const float*)d_in[12];
  const float* W2    = (const float*)d_in[13];
  const float* b2    = (const float*)d_in[14];
  const int*   ei    = (const int*)d_in[15];
  const int*   batch = (const int*)d_in[16];
  float* out = (float*)d_out;

  int N = in_sizes[0] / 2;
  int E = in_sizes[15] / 2;
  int G = out_size / NC;

  // ---- workspace layout (~75 MB for N=100k, E=1.6M) ----
  float* W = (float*)d_ws;
  size_t o = 0;
  float* gsum   = W + o; o += (size_t)2 * G;
  float* gcnt   = W + o; o += (size_t)G;
  int*   cnt    = (int*)(W + o); o += (size_t)N;
  int*   cursor = (int*)(W + o); o += (size_t)N;
  int*   dhist  = (int*)(W + o); o += (size_t)DBINS;
  size_t zero_bytes = o * 4;
  o = (o + 3) & ~(size_t)3;
  float* posc   = W + o; o += (size_t)2 * N;
  float* cthn   = W + o; o += (size_t)N;
  float* sthn   = W + o; o += (size_t)N;
  int*   off    = (int*)(W + o); o += (size_t)N + 1; o = (o + 3) & ~(size_t)3;
  int*   bsum   = (int*)(W + o); o += (size_t)1024;
  int*   dcur   = (int*)(W + o); o += (size_t)DBINS;
  int*   perm   = (int*)(W + o); o += (size_t)N; o = (o + 3) & ~(size_t)3;
  float4* csr   = (float4*)(W + o); o += (size_t)4 * E;
  uint2* yzgA   = (uint2*)(W + o); o += (size_t)32 * N;
  uint2* yzgB   = (uint2*)(W + o); o += (size_t)32 * N;
  float* xr     = W + o; o += (size_t)N * 32;
  float* xs     = W + o; o += (size_t)N * 16;
  (void)ws_size;

  hipMemsetAsync(d_ws, 0, zero_bytes, stream);
  hipMemsetAsync(d_out, 0, (size_t)out_size * 4, stream);

  int nbN  = (N + 255) / 256;
  int nbE  = (E + 255) / 256;
  int nbN16 = ((size_t)N * 16 + 255) / 256;
  int nbS  = (N + 1023) / 1024;
  int nbS3 = (N + 1 + 1023) / 1024;
  int nbF  = (N + 127) / 128;

  k_gsum_count<<<nbE, 256, 0, stream>>>(pos, batch, N, gsum, gcnt, ei, E, cnt);
  k_center_dhist_scan1<<<nbS, 1024, 0, stream>>>(pos, batch, N, gsum, gcnt,
                                                 posc, cthn, sthn, cnt, dhist, off, bsum);
  k_dscan_scan2<<<1, 1024, 0, stream>>>(dhist, dcur, bsum, nbS);
  k_dfill_scan3<<<nbS3, 1024, 0, stream>>>(off, bsum, N, E, cnt, dcur, perm, cursor);
  k_build<<<nbE, 256, 0, stream>>>(posc, ei, E, cursor, csr);
  k_init16<<<nbN16, 256, 0, stream>>>(N, off, csr, posc, Wer, wse, bse,
                                      Wmix, Ws1, bs1, Wgate, bgate,
                                      xr, xs, yzgA);

  // layer 0: read A, write B (fused pre for layer 1)
  k_layer<<<nbN16, 256, 0, stream>>>(N, off, csr, yzgA, perm,
                                     Wg, bg, Ws1, xr, xs,
                                     1, yzgB,
                                     Wmix + 256, Ws1 + 512, bs1 + 16, Wgate + 256, bgate + 16);
  // layer 1: read B, write A (fused pre for layer 2)
  k_layer<<<nbN16, 256, 0, stream>>>(N, off, csr, yzgB, perm,
                                     Wg + 256, bg + 16, Ws1 + 512, xr, xs,
                                     1, yzgA,
                                     Wmix + 512, Ws1 + 1024, bs1 + 32, Wgate + 512, bgate + 32);
  // layer 2: read A, no next
  k_layer<<<nbN16, 256, 0, stream>>>(N, off, csr, yzgA, perm,
                                     Wg + 512, bg + 32, Ws1 + 1024, xr, xs,
                                     0, yzgB,
                                     Wmix, Ws1, bs1, Wgate, bgate);

  k_final<<<nbF, 128, 0, stream>>>(N, xr, xs, cthn, sthn, batch, W1, b1, W2, b2, out);
}

// Round 21
// 549.011 us; speedup vs baseline: 1.1643x; 1.1643x over previous
//
#include <hip/hip_runtime.h>
#include <hip/hip_fp16.h>
#include <math.h>

#define NREP 16
#define RDIM 16
#define NS   16
#define NC   6
#define H1   144
#define DBINS 64

static __device__ __forceinline__ float leaky(float v) { return v > 0.0f ? v : 0.01f * v; }

// ---------- fused: per-graph mean (LDS-binned) + edge row count ----------
__global__ void k_gsum_count(const float* __restrict__ pos, const int* __restrict__ batch,
                             int N, float* __restrict__ gsum, float* __restrict__ gcnt,
                             const int* __restrict__ ei, int E, int* __restrict__ cnt) {
  int t = threadIdx.x;
  int e = blockIdx.x * 256 + t;
  if (e < E) atomicAdd(&cnt[ei[e]], 1);

  __shared__ float bx[320], by[320], bc[320];
  int start = blockIdx.x * 256;
  if (start >= N) return;
  int n = start + t;
  int b0 = batch[min(start, N - 1)];
  int span = batch[min(start + 255, N - 1)] - b0;
  bool useLds = (span < 320);
  if (useLds) {
    for (int i = t; i <= span; i += 256) { bx[i] = 0.f; by[i] = 0.f; bc[i] = 0.f; }
    __syncthreads();
    if (n < N) {
      int rb = batch[n] - b0;
      atomicAdd(&bx[rb], pos[2 * n + 0]);
      atomicAdd(&by[rb], pos[2 * n + 1]);
      atomicAdd(&bc[rb], 1.0f);
    }
    __syncthreads();
    for (int i = t; i <= span; i += 256) {
      if (bc[i] != 0.0f) {
        atomicAdd(&gsum[2 * (b0 + i) + 0], bx[i]);
        atomicAdd(&gsum[2 * (b0 + i) + 1], by[i]);
        atomicAdd(&gcnt[b0 + i], bc[i]);
      }
    }
  } else if (n < N) {
    int b = batch[n];
    atomicAdd(&gsum[2 * b + 0], pos[2 * n + 0]);
    atomicAdd(&gsum[2 * b + 1], pos[2 * n + 1]);
    atomicAdd(&gcnt[b], 1.0f);
  }
}

// ---------- fused: center + degree histogram + scan phase 1 ----------
__global__ void k_center_dhist_scan1(
    const float* __restrict__ pos, const int* __restrict__ batch, int N,
    const float* __restrict__ gsum, const float* __restrict__ gcnt,
    float* __restrict__ posc, float* __restrict__ cthn, float* __restrict__ sthn,
    const int* __restrict__ cnt, int* __restrict__ dhist,
    int* __restrict__ off, int* __restrict__ bsum) {
  __shared__ int lh[DBINS];
  __shared__ int sd[1024];
  int t = threadIdx.x;
  int i = blockIdx.x * 1024 + t;
  if (t < DBINS) lh[t] = 0;
  int v = (i < N) ? cnt[i] : 0;
  sd[t] = v;
  if (i < N) {
    int b = batch[i];
    float invc = 1.0f / fmaxf(gcnt[b], 1.0f);
    float px = pos[2 * i + 0] - gsum[2 * b + 0] * invc;
    float py = pos[2 * i + 1] - gsum[2 * b + 1] * invc;
    posc[2 * i + 0] = px;
    posc[2 * i + 1] = py;
    float r = sqrtf(px * px + py * py);
    if (r > 0.0f) { cthn[i] = px / r; sthn[i] = py / r; }
    else          { cthn[i] = 1.0f;  sthn[i] = 0.0f; }
  }
  __syncthreads();
  if (i < N) atomicAdd(&lh[min(v, DBINS - 1)], 1);
  for (int o = 1; o < 1024; o <<= 1) {
    int u = (t >= o) ? sd[t - o] : 0;
    __syncthreads();
    sd[t] += u;
    __syncthreads();
  }
  if (i < N) off[i] = sd[t] - v;
  if (t == 1023) bsum[blockIdx.x] = sd[1023];
  if (t < DBINS && lh[t] > 0) atomicAdd(&dhist[t], lh[t]);
}

// ---------- fused: degree-bin exclusive scan + block-sum exclusive scan ----------
__global__ void k_dscan_scan2(const int* __restrict__ dhist, int* __restrict__ dcur,
                              int* __restrict__ bsum, int nb) {
  __shared__ int s1[DBINS];
  __shared__ int s2[1024];
  int t = threadIdx.x;
  int v1 = (t < DBINS) ? dhist[t] : 0;
  if (t < DBINS) s1[t] = v1;
  int v2 = (t < nb) ? bsum[t] : 0;
  s2[t] = v2;
  __syncthreads();
  for (int o = 1; o < 1024; o <<= 1) {
    int u1 = (o < DBINS && t >= o && t < DBINS) ? s1[t - o] : 0;
    int u2 = (t >= o) ? s2[t - o] : 0;
    __syncthreads();
    if (o < DBINS && t < DBINS) s1[t] += u1;
    s2[t] += u2;
    __syncthreads();
  }
  if (t < DBINS) dcur[t] = s1[t] - v1;
  if (t < nb) bsum[t] = s2[t] - v2;
}

// ---------- fused: scan phase 3 + degree-sort fill + cursor=off init ----------
__global__ void k_dfill_scan3(int* __restrict__ off, const int* __restrict__ bsum,
                              int N, int E,
                              const int* __restrict__ cnt, int* __restrict__ dcur,
                              int* __restrict__ perm, int* __restrict__ cursor) {
  int t = threadIdx.x;
  int i = blockIdx.x * 1024 + t;
  if (i < N) {
    int ov = off[i] + bsum[blockIdx.x];
    off[i] = ov;
    cursor[i] = ov;                     // k_build slots start at off[i]
  }
  if (i == N) off[N] = E;

  __shared__ int lh[DBINS];
  __shared__ int base[DBINS];
  if (t < DBINS) lh[t] = 0;
  __syncthreads();
  int b = 0, lr = 0;
  if (i < N) {
    b = min(cnt[i], DBINS - 1);
    lr = atomicAdd(&lh[b], 1);
  }
  __syncthreads();
  if (t < DBINS && lh[t] > 0) base[t] = atomicAdd(&dcur[t], lh[t]);
  __syncthreads();
  if (i < N) perm[base[b] + lr] = i;
}

// csr[k] = (sp' = sqrt2*sin(pi d)/(d+eps), c2 = 2*cos(pi d), col-bits, d)
// Single-pass scatter: ~1 line-writeback per store (64B × E ≈ 102MB) — structural floor.
__global__ void k_build(const float* __restrict__ posc, const int* __restrict__ ei, int E,
                        int* __restrict__ cursor, float4* __restrict__ csr) {
  int e = blockIdx.x * blockDim.x + threadIdx.x;
  if (e >= E) return;
  int r = ei[e], cl = ei[E + e];
  float dx = posc[2 * r + 0] - posc[2 * cl + 0];
  float dy = posc[2 * r + 1] - posc[2 * cl + 1];
  float d = sqrtf(dx * dx + dy * dy);
  float sp, cp;
  sincospif(d, &sp, &cp);
  float spp = 1.41421356237309515f * sp / (d + 1e-8f);
  int p = atomicAdd(&cursor[r], 1);
  csr[p] = make_float4(spp, 2.0f * cp, __int_as_float(cl), d);
}

// ---------- fused node init + layer-0 pre: 16 lanes/node, unified uint2 yzg ----------
__global__ void __launch_bounds__(256) k_init16(
    int N, const int* __restrict__ off, const float4* __restrict__ csr,
    const float* __restrict__ posc,
    const float* __restrict__ Wer, const float* __restrict__ wse, const float* __restrict__ bse,
    const float* __restrict__ Wmix, const float* __restrict__ Ws1, const float* __restrict__ bs1,
    const float* __restrict__ Wgate, const float* __restrict__ bgate,
    float* __restrict__ xr, float* __restrict__ xs, uint2* __restrict__ yzg) {
  int idx = blockIdx.x * 256 + threadIdx.x;
  int n = idx >> 4, r = idx & 15;
  if (n >= N) return;
  int a = off[n], b = off[n + 1];
  float px = posc[2 * n + 0], py = posc[2 * n + 1];
  float C = 0.f, S = 0.f, D = 0.f;
  for (int k = a + r; k < b; k += 16) {      // lane r: coalesced 256B group reads
    float4 v = csr[k];
    int cl = __float_as_int(v.z);
    float d = v.w;
    if (d > 0.0f) {
      float inv = 1.0f / d;
      C += (px - posc[2 * cl + 0]) * inv;
      S += (py - posc[2 * cl + 1]) * inv;
    } else {
      C += 1.0f;
    }
    D += d;
  }
#pragma unroll
  for (int o = 1; o < 16; o <<= 1) {         // butterfly: all 16 lanes get full sums
    C += __shfl_xor(C, o, 16);
    S += __shfl_xor(S, o, 16);
    D += __shfl_xor(D, o, 16);
  }
  float id = 1.0f / fmaxf((float)(b - a), 1.0f);
  C *= id; S *= id;
  float dm = D * id;
  float w0 = Wer[2 * r], w1 = Wer[2 * r + 1];
  float2 x;
  x.x = C * w0 - S * w1;
  x.y = S * w0 + C * w1;
  ((float2*)xr)[(size_t)n * 16 + r] = x;
  float s_new = leaky(dm * wse[r] + bse[r]);
  xs[(size_t)n * 16 + r] = s_new;

  // fused layer-0 pre (shuffle form — same pattern as k_layer's write_next tail)
  float wmxn[16], wsan[16], wgtn[16];
#pragma unroll
  for (int q = 0; q < 16; q++) wmxn[q] = Wmix[r * 16 + q];
#pragma unroll
  for (int q = 0; q < 16; q++) wsan[q] = Ws1[q * 16 + r];
#pragma unroll
  for (int q = 0; q < 16; q++) wgtn[q] = Wgate[q * 16 + r];
  float y0 = 0.f, y1 = 0.f;
  float z = bs1[r], gtn = bgate[r];
#pragma unroll
  for (int j = 0; j < 16; j++) {
    float xj0 = __shfl(x.x, j, 16);
    float xj1 = __shfl(x.y, j, 16);
    float sj  = __shfl(s_new, j, 16);
    y0 += wmxn[j] * xj0;
    y1 += wmxn[j] * xj1;
    z  += wsan[j] * sj;
    gtn += wgtn[j] * sj;
  }
  gtn = 1.0f / (1.0f + __expf(-gtn));
  __half2 hA = __floats2half2_rn(y0, y1);
  __half2 hB = __floats2half2_rn(z, gtn);
  uint2 w2;
  w2.x = *(unsigned int*)&hA;
  w2.y = *(unsigned int*)&hB;
  yzg[(size_t)n * 16 + r] = w2;
}

// ---------- EqBlock layer + fused next-layer pre (shuffle form, yzg ping-pong) ----------
__global__ void __launch_bounds__(256) k_layer(
    int N, const int* __restrict__ off, const float4* __restrict__ csr,
    const uint2* __restrict__ yzg, const int* __restrict__ perm,
    const float* __restrict__ Wg, const float* __restrict__ bg,
    const float* __restrict__ Ws1,   // this layer; demb rows are 16..31
    float* xr, float* xs,
    int write_next, uint2* __restrict__ yzg_out,
    const float* __restrict__ Wmixn, const float* __restrict__ Ws1n,
    const float* __restrict__ bs1n,
    const float* __restrict__ Wgaten, const float* __restrict__ bgaten) {
  int idx = blockIdx.x * 256 + threadIdx.x;
  int g = idx >> 4, r = idx & 15;
  if (g >= N) return;
  int n = perm[g];                      // degree-sorted: waves get equal-degree nodes
  float wg[16], ws[16];
#pragma unroll
  for (int q = 0; q < 16; q++) wg[q] = Wg[q * 16 + r];
#pragma unroll
  for (int q = 0; q < 16; q++) ws[q] = Ws1[(16 + q) * 16 + r];
  float bgr = bg[r];

  int a = off[n], bnd = off[n + 1];
  float acc0 = 0.f, acc1 = 0.f, accs = 0.f;
  if (a < bnd) {
    int last = bnd - 1;
    float4 v0 = csr[a];
    float4 v1 = csr[min(a + 1, last)];
    float4 v2 = csr[min(a + 2, last)];
    uint2 Y0 = yzg[(size_t)__float_as_int(v0.z) * 16 + r];
    uint2 Y1 = yzg[(size_t)__float_as_int(v1.z) * 16 + r];
    for (int k = a; k < bnd; k++) {
      float4 v3 = csr[min(k + 3, last)];
      uint2 Y2 = yzg[(size_t)__float_as_int(v2.z) * 16 + r];
      float skm1 = 0.f, sk = v0.x, c2 = v0.y;
      float g1 = bgr, dot = 0.f;
#pragma unroll
      for (int q = 0; q < RDIM; q++) {
        g1  = __builtin_fmaf(sk, wg[q], g1);
        dot = __builtin_fmaf(sk, ws[q], dot);
        float sn = __builtin_fmaf(c2, sk, -skm1);
        skm1 = sk; sk = sn;
      }
      float2 f01 = __half22float2(*(__half2*)&Y0.x);
      float2 fzg = __half22float2(*(__half2*)&Y0.y);
      acc0 = __builtin_fmaf(g1, f01.x, acc0);
      acc1 = __builtin_fmaf(g1, f01.y, acc1);
      accs += leaky(dot + fzg.x);
      v0 = v1; v1 = v2; v2 = v3; Y0 = Y1; Y1 = Y2;
    }
  }
  float id = 1.0f / fmaxf((float)(bnd - a), 1.0f);
  uint2 Yg = yzg[(size_t)n * 16 + r];
  float gt = __half22float2(*(__half2*)&Yg.y).y;
  float2* xr2 = (float2*)xr;
  float2 x = xr2[(size_t)n * 16 + r];
  x.x += acc0 * id * gt;
  x.y += acc1 * id * gt;
  xr2[(size_t)n * 16 + r] = x;            // in-place safe: (n,r) written only by this thread
  float s_new = xs[(size_t)n * 16 + r] + accs * id;
  xs[(size_t)n * 16 + r] = s_new;

  if (write_next) {
    // fused k_pre for next layer: cross-r via 16-wide shuffles (same sum order as k_pre)
    float wmxn[16], wsan[16], wgtn[16];
#pragma unroll
    for (int q = 0; q < 16; q++) wmxn[q] = Wmixn[r * 16 + q];
#pragma unroll
    for (int q = 0; q < 16; q++) wsan[q] = Ws1n[q * 16 + r];
#pragma unroll
    for (int q = 0; q < 16; q++) wgtn[q] = Wgaten[q * 16 + r];
    float y0 = 0.f, y1 = 0.f;
    float z = bs1n[r], gtn = bgaten[r];
#pragma unroll
    for (int j = 0; j < 16; j++) {
      float xj0 = __shfl(x.x, j, 16);
      float xj1 = __shfl(x.y, j, 16);
      float sj  = __shfl(s_new, j, 16);
      y0 += wmxn[j] * xj0;
      y1 += wmxn[j] * xj1;
      z  += wsan[j] * sj;
      gtn += wgtn[j] * sj;
    }
    gtn = 1.0f / (1.0f + __expf(-gtn));
    __half2 hA = __floats2half2_rn(y0, y1);
    __half2 hB = __floats2half2_rn(z, gtn);
    uint2 w2;
    w2.x = *(unsigned int*)&hA;
    w2.y = *(unsigned int*)&hB;
    yzg_out[(size_t)n * 16 + r] = w2;
  }
}

// ---------- final rotate-out + MLP (W1^T in LDS, 2-h ILP) + binned graph sum ----------
__global__ void __launch_bounds__(128) k_final(
    int N, const float* __restrict__ xr, const float* __restrict__ xs,
    const float* __restrict__ cthn, const float* __restrict__ sthn,
    const int* __restrict__ batch,
    const float* __restrict__ W1, const float* __restrict__ b1,
    const float* __restrict__ W2, const float* __restrict__ b2,
    float* __restrict__ out) {
  __shared__ float W1t[48 * H1];
  __shared__ float W2s[H1 * 6];
  __shared__ float b1s[H1];
  __shared__ float obin[320 * 6];
  int t = threadIdx.x;
  for (int i = t; i < 48 * H1; i += 128) { int q = i / H1, h = i - q * H1; W1t[h * 48 + q] = W1[i]; }
  for (int i = t; i < H1 * 6; i += 128) W2s[i] = W2[i];
  for (int i = t; i < H1; i += 128) b1s[i] = b1[i];

  int start = blockIdx.x * 128;
  int n = start + t;
  int b0 = batch[min(start, N - 1)];
  int span = batch[min(start + 127, N - 1)] - b0;
  bool useLds = (span < 320);
  if (useLds) for (int i = t; i < (span + 1) * 6; i += 128) obin[i] = 0.f;
  __syncthreads();

  float u[NC];
  bool act = (n < N);
  if (act) {
    float4 xcv[12];
    const float4* xs4 = (const float4*)(xs + (size_t)n * NS);
#pragma unroll
    for (int j = 0; j < 4; j++) xcv[j] = xs4[j];
    float c = cthn[n], s = sthn[n];
    const float4* xr4 = (const float4*)(xr + (size_t)n * 32);
#pragma unroll
    for (int j = 0; j < 8; j++) {
      float4 v = xr4[j];
      xcv[4 + j] = make_float4(c * v.x - s * v.y, s * v.x + c * v.y,
                               c * v.z - s * v.w, s * v.z + c * v.w);
    }
#pragma unroll
    for (int q = 0; q < NC; q++) u[q] = b2[q];
    for (int h = 0; h < H1; h += 2) {
      const float4* w0 = (const float4*)&W1t[h * 48];
      const float4* w1 = (const float4*)&W1t[(h + 1) * 48];
      float4 a0 = make_float4(0.f, 0.f, 0.f, 0.f);
      float4 a1 = make_float4(0.f, 0.f, 0.f, 0.f);
#pragma unroll
      for (int j = 0; j < 12; j++) {
        float4 x = xcv[j];
        float4 w = w0[j];
        a0.x += x.x * w.x; a0.y += x.y * w.y; a0.z += x.z * w.z; a0.w += x.w * w.w;
        float4 v = w1[j];
        a1.x += x.x * v.x; a1.y += x.y * v.y; a1.z += x.z * v.z; a1.w += x.w * v.w;
      }
      float aa0 = leaky((a0.x + a0.y) + (a0.z + a0.w) + b1s[h]);
      float aa1 = leaky((a1.x + a1.y) + (a1.z + a1.w) + b1s[h + 1]);
#pragma unroll
      for (int q = 0; q < NC; q++)
        u[q] += aa0 * W2s[h * 6 + q] + aa1 * W2s[(h + 1) * 6 + q];
    }
  }
  if (useLds) {
    if (act) {
      int rb = batch[n] - b0;
#pragma unroll
      for (int q = 0; q < NC; q++) atomicAdd(&obin[rb * 6 + q], u[q]);
    }
    __syncthreads();
    for (int i = t; i < (span + 1) * 6; i += 128) atomicAdd(&out[b0 * 6 + i], obin[i]);
  } else if (act) {
    int b = batch[n];
#pragma unroll
    for (int q = 0; q < NC; q++) atomicAdd(&out[b * 6 + q], u[q]);
  }
}

extern "C" void kernel_launch(void* const* d_in, const int* in_sizes, int n_in,
                              void* d_out, int out_size, void* d_ws, size_t ws_size,
                              hipStream_t stream) {
  const float* pos   = (const float*)d_in[0];
  const float* Wer   = (const float*)d_in[1];
  const float* wse   = (const float*)d_in[2];
  const float* bse   = (const float*)d_in[3];
  const float* Wg    = (const float*)d_in[4];
  const float* bg    = (const float*)d_in[5];
  const float* Wmix  = (const float*)d_in[6];
  const float* Wgate = (const float*)d_in[7];
  const float* bgate = (const float*)d_in[8];
  const float* Ws1   = (const float*)d_in[9];
  const float* bs1   = (const float*)d_in[10];
  const float* W1    = (const float*)d_in[11];
  const float* b1    = (const float*)d_in[12];
  const float* W2    = (const float*)d_in[13];
  const float* b2    = (const float*)d_in[14];
  const int*   ei    = (const int*)d_in[15];
  const int*   batch = (const int*)d_in[16];
  float* out = (float*)d_out;

  int N = in_sizes[0] / 2;
  int E = in_sizes[15] / 2;
  int G = out_size / NC;

  // ---- workspace layout (~75 MB for N=100k, E=1.6M) ----
  float* W = (float*)d_ws;
  size_t o = 0;
  float* gsum   = W + o; o += (size_t)2 * G;
  float* gcnt   = W + o; o += (size_t)G;
  int*   cnt    = (int*)(W + o); o += (size_t)N;
  int*   cursor = (int*)(W + o); o += (size_t)N;
  int*   dhist  = (int*)(W + o); o += (size_t)DBINS;
  size_t zero_bytes = o * 4;
  o = (o + 3) & ~(size_t)3;
  float* posc   = W + o; o += (size_t)2 * N;
  float* cthn   = W + o; o += (size_t)N;
  float* sthn   = W + o; o += (size_t)N;
  int*   off    = (int*)(W + o); o += (size_t)N + 1; o = (o + 3) & ~(size_t)3;
  int*   bsum   = (int*)(W + o); o += (size_t)1024;
  int*   dcur   = (int*)(W + o); o += (size_t)DBINS;
  int*   perm   = (int*)(W + o); o += (size_t)N; o = (o + 3) & ~(size_t)3;
  float4* csr   = (float4*)(W + o); o += (size_t)4 * E;
  uint2* yzgA   = (uint2*)(W + o); o += (size_t)32 * N;
  uint2* yzgB   = (uint2*)(W + o); o += (size_t)32 * N;
  float* xr     = W + o; o += (size_t)N * 32;
  float* xs     = W + o; o += (size_t)N * 16;
  (void)ws_size;

  hipMemsetAsync(d_ws, 0, zero_bytes, stream);
  hipMemsetAsync(d_out, 0, (size_t)out_size * 4, stream);

  int nbN  = (N + 255) / 256;
  int nbE  = (E + 255) / 256;
  int nbN16 = ((size_t)N * 16 + 255) / 256;
  int nbS  = (N + 1023) / 1024;
  int nbS3 = (N + 1 + 1023) / 1024;
  int nbF  = (N + 127) / 128;

  k_gsum_count<<<nbE, 256, 0, stream>>>(pos, batch, N, gsum, gcnt, ei, E, cnt);
  k_center_dhist_scan1<<<nbS, 1024, 0, stream>>>(pos, batch, N, gsum, gcnt,
                                                 posc, cthn, sthn, cnt, dhist, off, bsum);
  k_dscan_scan2<<<1, 1024, 0, stream>>>(dhist, dcur, bsum, nbS);
  k_dfill_scan3<<<nbS3, 1024, 0, stream>>>(off, bsum, N, E, cnt, dcur, perm, cursor);
  k_build<<<nbE, 256, 0, stream>>>(posc, ei, E, cursor, csr);
  k_init16<<<nbN16, 256, 0, stream>>>(N, off, csr, posc, Wer, wse, bse,
                                      Wmix, Ws1, bs1, Wgate, bgate,
                                      xr, xs, yzgA);

  // layer 0: read A, write B (fused pre for layer 1)
  k_layer<<<nbN16, 256, 0, stream>>>(N, off, csr, yzgA, perm,
                                     Wg, bg, Ws1, xr, xs,
                                     1, yzgB,
                                     Wmix + 256, Ws1 + 512, bs1 + 16, Wgate + 256, bgate + 16);
  // layer 1: read B, write A (fused pre for layer 2)
  k_layer<<<nbN16, 256, 0, stream>>>(N, off, csr, yzgB, perm,
                                     Wg + 256, bg + 16, Ws1 + 512, xr, xs,
                                     1, yzgA,
                                     Wmix + 512, Ws1 + 1024, bs1 + 32, Wgate + 512, bgate + 32);
  // layer 2: read A, no next
  k_layer<<<nbN16, 256, 0, stream>>>(N, off, csr, yzgA, perm,
                                     Wg + 512, bg + 32, Ws1 + 1024, xr, xs,
                                     0, yzgB,
                                     Wmix, Ws1, bs1, Wgate, bgate);

  k_final<<<nbF, 128, 0, stream>>>(N, xr, xs, cthn, sthn, batch, W1, b1, W2, b2, out);
}

// Round 22
// 533.354 us; speedup vs baseline: 1.1985x; 1.0294x over previous
//
#include <hip/hip_runtime.h>
#include <hip/hip_fp16.h>
#include <math.h>

#define NREP 16
#define RDIM 16
#define NS   16
#define NC   6
#define H1   144
#define DBINS 64

static __device__ __forceinline__ float leaky(float v) { return v > 0.0f ? v : 0.01f * v; }

// ---------- fused: per-graph mean (LDS-binned) + edge row count ----------
__global__ void k_gsum_count(const float* __restrict__ pos, const int* __restrict__ batch,
                             int N, float* __restrict__ gsum, float* __restrict__ gcnt,
                             const int* __restrict__ ei, int E, int* __restrict__ cnt) {
  int t = threadIdx.x;
  int e = blockIdx.x * 256 + t;
  if (e < E) atomicAdd(&cnt[ei[e]], 1);

  __shared__ float bx[320], by[320], bc[320];
  int start = blockIdx.x * 256;
  if (start >= N) return;
  int n = start + t;
  int b0 = batch[min(start, N - 1)];
  int span = batch[min(start + 255, N - 1)] - b0;
  bool useLds = (span < 320);
  if (useLds) {
    for (int i = t; i <= span; i += 256) { bx[i] = 0.f; by[i] = 0.f; bc[i] = 0.f; }
    __syncthreads();
    if (n < N) {
      int rb = batch[n] - b0;
      atomicAdd(&bx[rb], pos[2 * n + 0]);
      atomicAdd(&by[rb], pos[2 * n + 1]);
      atomicAdd(&bc[rb], 1.0f);
    }
    __syncthreads();
    for (int i = t; i <= span; i += 256) {
      if (bc[i] != 0.0f) {
        atomicAdd(&gsum[2 * (b0 + i) + 0], bx[i]);
        atomicAdd(&gsum[2 * (b0 + i) + 1], by[i]);
        atomicAdd(&gcnt[b0 + i], bc[i]);
      }
    }
  } else if (n < N) {
    int b = batch[n];
    atomicAdd(&gsum[2 * b + 0], pos[2 * n + 0]);
    atomicAdd(&gsum[2 * b + 1], pos[2 * n + 1]);
    atomicAdd(&gcnt[b], 1.0f);
  }
}

// ---------- fused: center + degree histogram + scan phase 1 ----------
__global__ void k_center_dhist_scan1(
    const float* __restrict__ pos, const int* __restrict__ batch, int N,
    const float* __restrict__ gsum, const float* __restrict__ gcnt,
    float* __restrict__ posc, float* __restrict__ cthn, float* __restrict__ sthn,
    const int* __restrict__ cnt, int* __restrict__ dhist,
    int* __restrict__ off, int* __restrict__ bsum) {
  __shared__ int lh[DBINS];
  __shared__ int sd[1024];
  int t = threadIdx.x;
  int i = blockIdx.x * 1024 + t;
  if (t < DBINS) lh[t] = 0;
  int v = (i < N) ? cnt[i] : 0;
  sd[t] = v;
  if (i < N) {
    int b = batch[i];
    float invc = 1.0f / fmaxf(gcnt[b], 1.0f);
    float px = pos[2 * i + 0] - gsum[2 * b + 0] * invc;
    float py = pos[2 * i + 1] - gsum[2 * b + 1] * invc;
    posc[2 * i + 0] = px;
    posc[2 * i + 1] = py;
    float r = sqrtf(px * px + py * py);
    if (r > 0.0f) { cthn[i] = px / r; sthn[i] = py / r; }
    else          { cthn[i] = 1.0f;  sthn[i] = 0.0f; }
  }
  __syncthreads();
  if (i < N) atomicAdd(&lh[min(v, DBINS - 1)], 1);
  for (int o = 1; o < 1024; o <<= 1) {
    int u = (t >= o) ? sd[t - o] : 0;
    __syncthreads();
    sd[t] += u;
    __syncthreads();
  }
  if (i < N) off[i] = sd[t] - v;
  if (t == 1023) bsum[blockIdx.x] = sd[1023];
  if (t < DBINS && lh[t] > 0) atomicAdd(&dhist[t], lh[t]);
}

// ---------- fused: degree-bin exclusive scan + block-sum exclusive scan ----------
__global__ void k_dscan_scan2(const int* __restrict__ dhist, int* __restrict__ dcur,
                              int* __restrict__ bsum, int nb) {
  __shared__ int s1[DBINS];
  __shared__ int s2[1024];
  int t = threadIdx.x;
  int v1 = (t < DBINS) ? dhist[t] : 0;
  if (t < DBINS) s1[t] = v1;
  int v2 = (t < nb) ? bsum[t] : 0;
  s2[t] = v2;
  __syncthreads();
  for (int o = 1; o < 1024; o <<= 1) {
    int u1 = (o < DBINS && t >= o && t < DBINS) ? s1[t - o] : 0;
    int u2 = (t >= o) ? s2[t - o] : 0;
    __syncthreads();
    if (o < DBINS && t < DBINS) s1[t] += u1;
    s2[t] += u2;
    __syncthreads();
  }
  if (t < DBINS) dcur[t] = s1[t] - v1;
  if (t < nb) bsum[t] = s2[t] - v2;
}

// ---------- fused: scan phase 3 + degree-sort fill + cursor=off init ----------
__global__ void k_dfill_scan3(int* __restrict__ off, const int* __restrict__ bsum,
                              int N, int E,
                              const int* __restrict__ cnt, int* __restrict__ dcur,
                              int* __restrict__ perm, int* __restrict__ cursor) {
  int t = threadIdx.x;
  int i = blockIdx.x * 1024 + t;
  if (i < N) {
    int ov = off[i] + bsum[blockIdx.x];
    off[i] = ov;
    cursor[i] = ov;                     // k_build slots start at off[i]
  }
  if (i == N) off[N] = E;

  __shared__ int lh[DBINS];
  __shared__ int base[DBINS];
  if (t < DBINS) lh[t] = 0;
  __syncthreads();
  int b = 0, lr = 0;
  if (i < N) {
    b = min(cnt[i], DBINS - 1);
    lr = atomicAdd(&lh[b], 1);
  }
  __syncthreads();
  if (t < DBINS && lh[t] > 0) base[t] = atomicAdd(&dcur[t], lh[t]);
  __syncthreads();
  if (i < N) perm[base[b] + lr] = i;
}

// csr[k] = (sp' = sqrt2*sin(pi d)/(d+eps), c2 = 2*cos(pi d), col-bits, d)
// Single-pass scatter: ~1 line-writeback per store (64B × E ≈ 102MB) — structural floor.
__global__ void k_build(const float* __restrict__ posc, const int* __restrict__ ei, int E,
                        int* __restrict__ cursor, float4* __restrict__ csr) {
  int e = blockIdx.x * blockDim.x + threadIdx.x;
  if (e >= E) return;
  int r = ei[e], cl = ei[E + e];
  float dx = posc[2 * r + 0] - posc[2 * cl + 0];
  float dy = posc[2 * r + 1] - posc[2 * cl + 1];
  float d = sqrtf(dx * dx + dy * dy);
  float sp, cp;
  sincospif(d, &sp, &cp);
  float spp = 1.41421356237309515f * sp / (d + 1e-8f);
  int p = atomicAdd(&cursor[r], 1);
  csr[p] = make_float4(spp, 2.0f * cp, __int_as_float(cl), d);
}

// ---------- fused node init + layer-0 pre: 16 lanes/node, unified uint2 yzg ----------
__global__ void __launch_bounds__(256) k_init16(
    int N, const int* __restrict__ off, const float4* __restrict__ csr,
    const float* __restrict__ posc,
    const float* __restrict__ Wer, const float* __restrict__ wse, const float* __restrict__ bse,
    const float* __restrict__ Wmix, const float* __restrict__ Ws1, const float* __restrict__ bs1,
    const float* __restrict__ Wgate, const float* __restrict__ bgate,
    float* __restrict__ xr, float* __restrict__ xs, uint2* __restrict__ yzg) {
  int idx = blockIdx.x * 256 + threadIdx.x;
  int n = idx >> 4, r = idx & 15;
  if (n >= N) return;
  int a = off[n], b = off[n + 1];
  float px = posc[2 * n + 0], py = posc[2 * n + 1];
  float C = 0.f, S = 0.f, D = 0.f;
  for (int k = a + r; k < b; k += 16) {      // lane r: coalesced 256B group reads
    float4 v = csr[k];
    int cl = __float_as_int(v.z);
    float d = v.w;
    if (d > 0.0f) {
      float inv = 1.0f / d;
      C += (px - posc[2 * cl + 0]) * inv;
      S += (py - posc[2 * cl + 1]) * inv;
    } else {
      C += 1.0f;
    }
    D += d;
  }
#pragma unroll
  for (int o = 1; o < 16; o <<= 1) {         // butterfly: all 16 lanes get full sums
    C += __shfl_xor(C, o, 16);
    S += __shfl_xor(S, o, 16);
    D += __shfl_xor(D, o, 16);
  }
  float id = 1.0f / fmaxf((float)(b - a), 1.0f);
  C *= id; S *= id;
  float dm = D * id;
  float w0 = Wer[2 * r], w1 = Wer[2 * r + 1];
  float2 x;
  x.x = C * w0 - S * w1;
  x.y = S * w0 + C * w1;
  ((float2*)xr)[(size_t)n * 16 + r] = x;
  float s_new = leaky(dm * wse[r] + bse[r]);
  xs[(size_t)n * 16 + r] = s_new;

  // fused layer-0 pre (shuffle form — same pattern as k_layer's write_next tail)
  float wmxn[16], wsan[16], wgtn[16];
#pragma unroll
  for (int q = 0; q < 16; q++) wmxn[q] = Wmix[r * 16 + q];
#pragma unroll
  for (int q = 0; q < 16; q++) wsan[q] = Ws1[q * 16 + r];
#pragma unroll
  for (int q = 0; q < 16; q++) wgtn[q] = Wgate[q * 16 + r];
  float y0 = 0.f, y1 = 0.f;
  float z = bs1[r], gtn = bgate[r];
#pragma unroll
  for (int j = 0; j < 16; j++) {
    float xj0 = __shfl(x.x, j, 16);
    float xj1 = __shfl(x.y, j, 16);
    float sj  = __shfl(s_new, j, 16);
    y0 += wmxn[j] * xj0;
    y1 += wmxn[j] * xj1;
    z  += wsan[j] * sj;
    gtn += wgtn[j] * sj;
  }
  gtn = 1.0f / (1.0f + __expf(-gtn));
  __half2 hA = __floats2half2_rn(y0, y1);
  __half2 hB = __floats2half2_rn(z, gtn);
  uint2 w2;
  w2.x = *(unsigned int*)&hA;
  w2.y = *(unsigned int*)&hB;
  yzg[(size_t)n * 16 + r] = w2;
}

// ---------- EqBlock layer + fused next-layer pre (shuffle form, yzg ping-pong) ----------
__global__ void __launch_bounds__(256) k_layer(
    int N, const int* __restrict__ off, const float4* __restrict__ csr,
    const uint2* __restrict__ yzg, const int* __restrict__ perm,
    const float* __restrict__ Wg, const float* __restrict__ bg,
    const float* __restrict__ Ws1,   // this layer; demb rows are 16..31
    float* xr, float* xs,
    int write_next, uint2* __restrict__ yzg_out,
    const float* __restrict__ Wmixn, const float* __restrict__ Ws1n,
    const float* __restrict__ bs1n,
    const float* __restrict__ Wgaten, const float* __restrict__ bgaten) {
  int idx = blockIdx.x * 256 + threadIdx.x;
  int g = idx >> 4, r = idx & 15;
  if (g >= N) return;
  int n = perm[g];                      // degree-sorted: waves get equal-degree nodes
  float wg[16], ws[16];
#pragma unroll
  for (int q = 0; q < 16; q++) wg[q] = Wg[q * 16 + r];
#pragma unroll
  for (int q = 0; q < 16; q++) ws[q] = Ws1[(16 + q) * 16 + r];
  float bgr = bg[r];

  int a = off[n], bnd = off[n + 1];
  float acc0 = 0.f, acc1 = 0.f, accs = 0.f;
  if (a < bnd) {
    int last = bnd - 1;
    float4 v0 = csr[a];
    float4 v1 = csr[min(a + 1, last)];
    float4 v2 = csr[min(a + 2, last)];
    uint2 Y0 = yzg[(size_t)__float_as_int(v0.z) * 16 + r];
    uint2 Y1 = yzg[(size_t)__float_as_int(v1.z) * 16 + r];
    for (int k = a; k < bnd; k++) {
      float4 v3 = csr[min(k + 3, last)];
      uint2 Y2 = yzg[(size_t)__float_as_int(v2.z) * 16 + r];
      float skm1 = 0.f, sk = v0.x, c2 = v0.y;
      float g1 = bgr, dot = 0.f;
#pragma unroll
      for (int q = 0; q < RDIM; q++) {
        g1  = __builtin_fmaf(sk, wg[q], g1);
        dot = __builtin_fmaf(sk, ws[q], dot);
        float sn = __builtin_fmaf(c2, sk, -skm1);
        skm1 = sk; sk = sn;
      }
      float2 f01 = __half22float2(*(__half2*)&Y0.x);
      float2 fzg = __half22float2(*(__half2*)&Y0.y);
      acc0 = __builtin_fmaf(g1, f01.x, acc0);
      acc1 = __builtin_fmaf(g1, f01.y, acc1);
      accs += leaky(dot + fzg.x);
      v0 = v1; v1 = v2; v2 = v3; Y0 = Y1; Y1 = Y2;
    }
  }
  float id = 1.0f / fmaxf((float)(bnd - a), 1.0f);
  uint2 Yg = yzg[(size_t)n * 16 + r];
  float gt = __half22float2(*(__half2*)&Yg.y).y;
  float2* xr2 = (float2*)xr;
  float2 x = xr2[(size_t)n * 16 + r];
  x.x += acc0 * id * gt;
  x.y += acc1 * id * gt;
  xr2[(size_t)n * 16 + r] = x;            // in-place safe: (n,r) written only by this thread
  float s_new = xs[(size_t)n * 16 + r] + accs * id;
  xs[(size_t)n * 16 + r] = s_new;

  if (write_next) {
    // fused k_pre for next layer: cross-r via 16-wide shuffles (same sum order as k_pre)
    float wmxn[16], wsan[16], wgtn[16];
#pragma unroll
    for (int q = 0; q < 16; q++) wmxn[q] = Wmixn[r * 16 + q];
#pragma unroll
    for (int q = 0; q < 16; q++) wsan[q] = Ws1n[q * 16 + r];
#pragma unroll
    for (int q = 0; q < 16; q++) wgtn[q] = Wgaten[q * 16 + r];
    float y0 = 0.f, y1 = 0.f;
    float z = bs1n[r], gtn = bgaten[r];
#pragma unroll
    for (int j = 0; j < 16; j++) {
      float xj0 = __shfl(x.x, j, 16);
      float xj1 = __shfl(x.y, j, 16);
      float sj  = __shfl(s_new, j, 16);
      y0 += wmxn[j] * xj0;
      y1 += wmxn[j] * xj1;
      z  += wsan[j] * sj;
      gtn += wgtn[j] * sj;
    }
    gtn = 1.0f / (1.0f + __expf(-gtn));
    __half2 hA = __floats2half2_rn(y0, y1);
    __half2 hB = __floats2half2_rn(z, gtn);
    uint2 w2;
    w2.x = *(unsigned int*)&hA;
    w2.y = *(unsigned int*)&hB;
    yzg_out[(size_t)n * 16 + r] = w2;
  }
}

// ---------- final rotate-out + MLP (wave-uniform scalar weight loads) + binned graph sum ----------
// W1/W2/b1/b2 are read at wave-uniform addresses (h is uniform) -> scalar pipe / L1
// broadcast, freeing the LDS pipe entirely (prev: 1728 ds_read_b128/wave = the bottleneck).
__global__ void __launch_bounds__(128) k_final(
    int N, const float* __restrict__ xr, const float* __restrict__ xs,
    const float* __restrict__ cthn, const float* __restrict__ sthn,
    const int* __restrict__ batch,
    const float* __restrict__ W1, const float* __restrict__ b1,
    const float* __restrict__ W2, const float* __restrict__ b2,
    float* __restrict__ out) {
  __shared__ float obin[320 * 6];
  int t = threadIdx.x;
  int start = blockIdx.x * 128;
  int n = start + t;
  int b0 = batch[min(start, N - 1)];
  int span = batch[min(start + 127, N - 1)] - b0;
  bool useLds = (span < 320);
  if (useLds) for (int i = t; i < (span + 1) * 6; i += 128) obin[i] = 0.f;
  __syncthreads();

  float u[NC];
  bool act = (n < N);
  if (act) {
    float xc[48];
    const float4* xs4 = (const float4*)(xs + (size_t)n * NS);
#pragma unroll
    for (int j = 0; j < 4; j++) {
      float4 v = xs4[j];
      xc[4 * j + 0] = v.x; xc[4 * j + 1] = v.y; xc[4 * j + 2] = v.z; xc[4 * j + 3] = v.w;
    }
    float c = cthn[n], s = sthn[n];
    const float4* xr4 = (const float4*)(xr + (size_t)n * 32);
#pragma unroll
    for (int j = 0; j < 8; j++) {
      float4 v = xr4[j];
      xc[16 + 4 * j + 0] = c * v.x - s * v.y;
      xc[16 + 4 * j + 1] = s * v.x + c * v.y;
      xc[16 + 4 * j + 2] = c * v.z - s * v.w;
      xc[16 + 4 * j + 3] = s * v.z + c * v.w;
    }
#pragma unroll
    for (int q = 0; q < NC; q++) u[q] = b2[q];
    for (int h = 0; h < H1; h += 4) {
      float a0 = b1[h + 0], a1 = b1[h + 1], a2 = b1[h + 2], a3 = b1[h + 3];
#pragma unroll
      for (int q = 0; q < 48; q++) {
        // uniform address (h,q uniform) -> s_load_dwordx4, cached in K$/L1
        float4 w = *(const float4*)(W1 + (size_t)q * H1 + h);
        float x = xc[q];
        a0 = __builtin_fmaf(x, w.x, a0);
        a1 = __builtin_fmaf(x, w.y, a1);
        a2 = __builtin_fmaf(x, w.z, a2);
        a3 = __builtin_fmaf(x, w.w, a3);
      }
      a0 = leaky(a0); a1 = leaky(a1); a2 = leaky(a2); a3 = leaky(a3);
#pragma unroll
      for (int q = 0; q < NC; q++)
        u[q] += a0 * W2[(h + 0) * 6 + q] + a1 * W2[(h + 1) * 6 + q]
              + a2 * W2[(h + 2) * 6 + q] + a3 * W2[(h + 3) * 6 + q];
    }
  }
  if (useLds) {
    if (act) {
      int rb = batch[n] - b0;
#pragma unroll
      for (int q = 0; q < NC; q++) atomicAdd(&obin[rb * 6 + q], u[q]);
    }
    __syncthreads();
    for (int i = t; i < (span + 1) * 6; i += 128) atomicAdd(&out[b0 * 6 + i], obin[i]);
  } else if (act) {
    int b = batch[n];
#pragma unroll
    for (int q = 0; q < NC; q++) atomicAdd(&out[b * 6 + q], u[q]);
  }
}

extern "C" void kernel_launch(void* const* d_in, const int* in_sizes, int n_in,
                              void* d_out, int out_size, void* d_ws, size_t ws_size,
                              hipStream_t stream) {
  const float* pos   = (const float*)d_in[0];
  const float* Wer   = (const float*)d_in[1];
  const float* wse   = (const float*)d_in[2];
  const float* bse   = (const float*)d_in[3];
  const float* Wg    = (const float*)d_in[4];
  const float* bg    = (const float*)d_in[5];
  const float* Wmix  = (const float*)d_in[6];
  const float* Wgate = (const float*)d_in[7];
  const float* bgate = (const float*)d_in[8];
  const float* Ws1   = (const float*)d_in[9];
  const float* bs1   = (const float*)d_in[10];
  const float* W1    = (const float*)d_in[11];
  const float* b1    = (const float*)d_in[12];
  const float* W2    = (const float*)d_in[13];
  const float* b2    = (const float*)d_in[14];
  const int*   ei    = (const int*)d_in[15];
  const int*   batch = (const int*)d_in[16];
  float* out = (float*)d_out;

  int N = in_sizes[0] / 2;
  int E = in_sizes[15] / 2;
  int G = out_size / NC;

  // ---- workspace layout (~75 MB for N=100k, E=1.6M) ----
  float* W = (float*)d_ws;
  size_t o = 0;
  float* gsum   = W + o; o += (size_t)2 * G;
  float* gcnt   = W + o; o += (size_t)G;
  int*   cnt    = (int*)(W + o); o += (size_t)N;
  int*   cursor = (int*)(W + o); o += (size_t)N;
  int*   dhist  = (int*)(W + o); o += (size_t)DBINS;
  size_t zero_bytes = o * 4;
  o = (o + 3) & ~(size_t)3;
  float* posc   = W + o; o += (size_t)2 * N;
  float* cthn   = W + o; o += (size_t)N;
  float* sthn   = W + o; o += (size_t)N;
  int*   off    = (int*)(W + o); o += (size_t)N + 1; o = (o + 3) & ~(size_t)3;
  int*   bsum   = (int*)(W + o); o += (size_t)1024;
  int*   dcur   = (int*)(W + o); o += (size_t)DBINS;
  int*   perm   = (int*)(W + o); o += (size_t)N; o = (o + 3) & ~(size_t)3;
  float4* csr   = (float4*)(W + o); o += (size_t)4 * E;
  uint2* yzgA   = (uint2*)(W + o); o += (size_t)32 * N;
  uint2* yzgB   = (uint2*)(W + o); o += (size_t)32 * N;
  float* xr     = W + o; o += (size_t)N * 32;
  float* xs     = W + o; o += (size_t)N * 16;
  (void)ws_size;

  hipMemsetAsync(d_ws, 0, zero_bytes, stream);
  hipMemsetAsync(d_out, 0, (size_t)out_size * 4, stream);

  int nbN  = (N + 255) / 256;
  int nbE  = (E + 255) / 256;
  int nbN16 = ((size_t)N * 16 + 255) / 256;
  int nbS  = (N + 1023) / 1024;
  int nbS3 = (N + 1 + 1023) / 1024;
  int nbF  = (N + 127) / 128;

  k_gsum_count<<<nbE, 256, 0, stream>>>(pos, batch, N, gsum, gcnt, ei, E, cnt);
  k_center_dhist_scan1<<<nbS, 1024, 0, stream>>>(pos, batch, N, gsum, gcnt,
                                                 posc, cthn, sthn, cnt, dhist, off, bsum);
  k_dscan_scan2<<<1, 1024, 0, stream>>>(dhist, dcur, bsum, nbS);
  k_dfill_scan3<<<nbS3, 1024, 0, stream>>>(off, bsum, N, E, cnt, dcur, perm, cursor);
  k_build<<<nbE, 256, 0, stream>>>(posc, ei, E, cursor, csr);
  k_init16<<<nbN16, 256, 0, stream>>>(N, off, csr, posc, Wer, wse, bse,
                                      Wmix, Ws1, bs1, Wgate, bgate,
                                      xr, xs, yzgA);

  // layer 0: read A, write B (fused pre for layer 1)
  k_layer<<<nbN16, 256, 0, stream>>>(N, off, csr, yzgA, perm,
                                     Wg, bg, Ws1, xr, xs,
                                     1, yzgB,
                                     Wmix + 256, Ws1 + 512, bs1 + 16, Wgate + 256, bgate + 16);
  // layer 1: read B, write A (fused pre for layer 2)
  k_layer<<<nbN16, 256, 0, stream>>>(N, off, csr, yzgB, perm,
                                     Wg + 256, bg + 16, Ws1 + 512, xr, xs,
                                     1, yzgA,
                                     Wmix + 512, Ws1 + 1024, bs1 + 32, Wgate + 512, bgate + 32);
  // layer 2: read A, no next
  k_layer<<<nbN16, 256, 0, stream>>>(N, off, csr, yzgA, perm,
                                     Wg + 512, bg + 32, Ws1 + 1024, xr, xs,
                                     0, yzgB,
                                     Wmix, Ws1, bs1, Wgate, bgate);

  k_final<<<nbF, 128, 0, stream>>>(N, xr, xs, cthn, sthn, batch, W1, b1, W2, b2, out);
}

// Round 23
// 531.114 us; speedup vs baseline: 1.2035x; 1.0042x over previous
//
#include <hip/hip_runtime.h>
#include <hip/hip_fp16.h>
#include <math.h>

#define NREP 16
#define RDIM 16
#define NS   16
#define NC   6
#define H1   144
#define DBINS 64

static __device__ __forceinline__ float leaky(float v) { return v > 0.0f ? v : 0.01f * v; }

// ---------- fused: per-graph mean (LDS-binned) + edge row count ----------
__global__ void k_gsum_count(const float* __restrict__ pos, const int* __restrict__ batch,
                             int N, float* __restrict__ gsum, float* __restrict__ gcnt,
                             const int* __restrict__ ei, int E, int* __restrict__ cnt) {
  int t = threadIdx.x;
  int e = blockIdx.x * 256 + t;
  if (e < E) atomicAdd(&cnt[ei[e]], 1);

  __shared__ float bx[320], by[320], bc[320];
  int start = blockIdx.x * 256;
  if (start >= N) return;
  int n = start + t;
  int b0 = batch[min(start, N - 1)];
  int span = batch[min(start + 255, N - 1)] - b0;
  bool useLds = (span < 320);
  if (useLds) {
    for (int i = t; i <= span; i += 256) { bx[i] = 0.f; by[i] = 0.f; bc[i] = 0.f; }
    __syncthreads();
    if (n < N) {
      int rb = batch[n] - b0;
      atomicAdd(&bx[rb], pos[2 * n + 0]);
      atomicAdd(&by[rb], pos[2 * n + 1]);
      atomicAdd(&bc[rb], 1.0f);
    }
    __syncthreads();
    for (int i = t; i <= span; i += 256) {
      if (bc[i] != 0.0f) {
        atomicAdd(&gsum[2 * (b0 + i) + 0], bx[i]);
        atomicAdd(&gsum[2 * (b0 + i) + 1], by[i]);
        atomicAdd(&gcnt[b0 + i], bc[i]);
      }
    }
  } else if (n < N) {
    int b = batch[n];
    atomicAdd(&gsum[2 * b + 0], pos[2 * n + 0]);
    atomicAdd(&gsum[2 * b + 1], pos[2 * n + 1]);
    atomicAdd(&gcnt[b], 1.0f);
  }
}

// ---------- fused: center + degree histogram + scan phase 1 ----------
__global__ void k_center_dhist_scan1(
    const float* __restrict__ pos, const int* __restrict__ batch, int N,
    const float* __restrict__ gsum, const float* __restrict__ gcnt,
    float* __restrict__ posc, float* __restrict__ cthn, float* __restrict__ sthn,
    const int* __restrict__ cnt, int* __restrict__ dhist,
    int* __restrict__ off, int* __restrict__ bsum) {
  __shared__ int lh[DBINS];
  __shared__ int sd[1024];
  int t = threadIdx.x;
  int i = blockIdx.x * 1024 + t;
  if (t < DBINS) lh[t] = 0;
  int v = (i < N) ? cnt[i] : 0;
  sd[t] = v;
  if (i < N) {
    int b = batch[i];
    float invc = 1.0f / fmaxf(gcnt[b], 1.0f);
    float px = pos[2 * i + 0] - gsum[2 * b + 0] * invc;
    float py = pos[2 * i + 1] - gsum[2 * b + 1] * invc;
    posc[2 * i + 0] = px;
    posc[2 * i + 1] = py;
    float r = sqrtf(px * px + py * py);
    if (r > 0.0f) { cthn[i] = px / r; sthn[i] = py / r; }
    else          { cthn[i] = 1.0f;  sthn[i] = 0.0f; }
  }
  __syncthreads();
  if (i < N) atomicAdd(&lh[min(v, DBINS - 1)], 1);
  for (int o = 1; o < 1024; o <<= 1) {
    int u = (t >= o) ? sd[t - o] : 0;
    __syncthreads();
    sd[t] += u;
    __syncthreads();
  }
  if (i < N) off[i] = sd[t] - v;
  if (t == 1023) bsum[blockIdx.x] = sd[1023];
  if (t < DBINS && lh[t] > 0) atomicAdd(&dhist[t], lh[t]);
}

// ---------- fused: degree-bin exclusive scan + block-sum exclusive scan ----------
__global__ void k_dscan_scan2(const int* __restrict__ dhist, int* __restrict__ dcur,
                              int* __restrict__ bsum, int nb) {
  __shared__ int s1[DBINS];
  __shared__ int s2[1024];
  int t = threadIdx.x;
  int v1 = (t < DBINS) ? dhist[t] : 0;
  if (t < DBINS) s1[t] = v1;
  int v2 = (t < nb) ? bsum[t] : 0;
  s2[t] = v2;
  __syncthreads();
  for (int o = 1; o < 1024; o <<= 1) {
    int u1 = (o < DBINS && t >= o && t < DBINS) ? s1[t - o] : 0;
    int u2 = (t >= o) ? s2[t - o] : 0;
    __syncthreads();
    if (o < DBINS && t < DBINS) s1[t] += u1;
    s2[t] += u2;
    __syncthreads();
  }
  if (t < DBINS) dcur[t] = s1[t] - v1;
  if (t < nb) bsum[t] = s2[t] - v2;
}

// ---------- fused: scan phase 3 + degree-sort fill + cursor=off init ----------
__global__ void k_dfill_scan3(int* __restrict__ off, const int* __restrict__ bsum,
                              int N, int E,
                              const int* __restrict__ cnt, int* __restrict__ dcur,
                              int* __restrict__ perm, int* __restrict__ cursor) {
  int t = threadIdx.x;
  int i = blockIdx.x * 1024 + t;
  if (i < N) {
    int ov = off[i] + bsum[blockIdx.x];
    off[i] = ov;
    cursor[i] = ov;                     // k_build slots start at off[i]
  }
  if (i == N) off[N] = E;

  __shared__ int lh[DBINS];
  __shared__ int base[DBINS];
  if (t < DBINS) lh[t] = 0;
  __syncthreads();
  int b = 0, lr = 0;
  if (i < N) {
    b = min(cnt[i], DBINS - 1);
    lr = atomicAdd(&lh[b], 1);
  }
  __syncthreads();
  if (t < DBINS && lh[t] > 0) base[t] = atomicAdd(&dcur[t], lh[t]);
  __syncthreads();
  if (i < N) perm[base[b] + lr] = i;
}

// csr[k] = (sp' = sqrt2*sin(pi d)/(d+eps), c2 = 2*cos(pi d), col-bits, d)
// Single-pass scatter: ~1 line-writeback per store (64B × E ≈ 102MB) — structural floor.
__global__ void k_build(const float* __restrict__ posc, const int* __restrict__ ei, int E,
                        int* __restrict__ cursor, float4* __restrict__ csr) {
  int e = blockIdx.x * blockDim.x + threadIdx.x;
  if (e >= E) return;
  int r = ei[e], cl = ei[E + e];
  float dx = posc[2 * r + 0] - posc[2 * cl + 0];
  float dy = posc[2 * r + 1] - posc[2 * cl + 1];
  float d = sqrtf(dx * dx + dy * dy);
  float sp, cp;
  sincospif(d, &sp, &cp);
  float spp = 1.41421356237309515f * sp / (d + 1e-8f);
  int p = atomicAdd(&cursor[r], 1);
  csr[p] = make_float4(spp, 2.0f * cp, __int_as_float(cl), d);
}

// ---------- fused node init + layer-0 pre: 16 lanes/node, unified uint2 yzg ----------
__global__ void __launch_bounds__(256) k_init16(
    int N, const int* __restrict__ off, const float4* __restrict__ csr,
    const float* __restrict__ posc,
    const float* __restrict__ Wer, const float* __restrict__ wse, const float* __restrict__ bse,
    const float* __restrict__ Wmix, const float* __restrict__ Ws1, const float* __restrict__ bs1,
    const float* __restrict__ Wgate, const float* __restrict__ bgate,
    float* __restrict__ xr, float* __restrict__ xs, uint2* __restrict__ yzg) {
  int idx = blockIdx.x * 256 + threadIdx.x;
  int n = idx >> 4, r = idx & 15;
  if (n >= N) return;
  int a = off[n], b = off[n + 1];
  float px = posc[2 * n + 0], py = posc[2 * n + 1];
  float C = 0.f, S = 0.f, D = 0.f;
  for (int k = a + r; k < b; k += 16) {      // lane r: coalesced 256B group reads
    float4 v = csr[k];
    int cl = __float_as_int(v.z);
    float d = v.w;
    if (d > 0.0f) {
      float inv = 1.0f / d;
      C += (px - posc[2 * cl + 0]) * inv;
      S += (py - posc[2 * cl + 1]) * inv;
    } else {
      C += 1.0f;
    }
    D += d;
  }
#pragma unroll
  for (int o = 1; o < 16; o <<= 1) {         // butterfly: all 16 lanes get full sums
    C += __shfl_xor(C, o, 16);
    S += __shfl_xor(S, o, 16);
    D += __shfl_xor(D, o, 16);
  }
  float id = 1.0f / fmaxf((float)(b - a), 1.0f);
  C *= id; S *= id;
  float dm = D * id;
  float w0 = Wer[2 * r], w1 = Wer[2 * r + 1];
  float2 x;
  x.x = C * w0 - S * w1;
  x.y = S * w0 + C * w1;
  ((float2*)xr)[(size_t)n * 16 + r] = x;
  float s_new = leaky(dm * wse[r] + bse[r]);
  xs[(size_t)n * 16 + r] = s_new;

  // fused layer-0 pre (shuffle form — same pattern as k_layer's write_next tail)
  float wmxn[16], wsan[16], wgtn[16];
#pragma unroll
  for (int q = 0; q < 16; q++) wmxn[q] = Wmix[r * 16 + q];
#pragma unroll
  for (int q = 0; q < 16; q++) wsan[q] = Ws1[q * 16 + r];
#pragma unroll
  for (int q = 0; q < 16; q++) wgtn[q] = Wgate[q * 16 + r];
  float y0 = 0.f, y1 = 0.f;
  float z = bs1[r], gtn = bgate[r];
#pragma unroll
  for (int j = 0; j < 16; j++) {
    float xj0 = __shfl(x.x, j, 16);
    float xj1 = __shfl(x.y, j, 16);
    float sj  = __shfl(s_new, j, 16);
    y0 += wmxn[j] * xj0;
    y1 += wmxn[j] * xj1;
    z  += wsan[j] * sj;
    gtn += wgtn[j] * sj;
  }
  gtn = 1.0f / (1.0f + __expf(-gtn));
  __half2 hA = __floats2half2_rn(y0, y1);
  __half2 hB = __floats2half2_rn(z, gtn);
  uint2 w2;
  w2.x = *(unsigned int*)&hA;
  w2.y = *(unsigned int*)&hB;
  yzg[(size_t)n * 16 + r] = w2;
}

// ---------- EqBlock layer + fused next-layer pre (peeled prefetch loop, 32-bit yzg idx) ----------
__global__ void __launch_bounds__(256) k_layer(
    int N, const int* __restrict__ off, const float4* __restrict__ csr,
    const uint2* __restrict__ yzg, const int* __restrict__ perm,
    const float* __restrict__ Wg, const float* __restrict__ bg,
    const float* __restrict__ Ws1,   // this layer; demb rows are 16..31
    float* xr, float* xs,
    int write_next, uint2* __restrict__ yzg_out,
    const float* __restrict__ Wmixn, const float* __restrict__ Ws1n,
    const float* __restrict__ bs1n,
    const float* __restrict__ Wgaten, const float* __restrict__ bgaten) {
  int idx = blockIdx.x * 256 + threadIdx.x;
  int g = idx >> 4, r = idx & 15;
  if (g >= N) return;
  int n = perm[g];                      // degree-sorted: waves get equal-degree nodes
  float wg[16], ws[16];
#pragma unroll
  for (int q = 0; q < 16; q++) wg[q] = Wg[q * 16 + r];
#pragma unroll
  for (int q = 0; q < 16; q++) ws[q] = Ws1[(16 + q) * 16 + r];
  float bgr = bg[r];

  int a = off[n], bnd = off[n + 1];
  float acc0 = 0.f, acc1 = 0.f, accs = 0.f;
  if (a < bnd) {
    int last = bnd - 1;
    float4 v0 = csr[a];
    float4 v1 = csr[min(a + 1, last)];
    float4 v2 = csr[min(a + 2, last)];
    uint2 Y0 = yzg[(__float_as_int(v0.z) << 4) + r];
    uint2 Y1 = yzg[(__float_as_int(v1.z) << 4) + r];
    int k = a;
    // main loop: all prefetches provably in-range (no clamps)
    for (; k + 3 < bnd; k++) {
      float4 v3 = csr[k + 3];
      uint2 Y2 = yzg[(__float_as_int(v2.z) << 4) + r];
      float skm1 = 0.f, sk = v0.x, c2 = v0.y;
      float g1 = bgr, dot = 0.f;
#pragma unroll
      for (int q = 0; q < RDIM; q++) {
        g1  = __builtin_fmaf(sk, wg[q], g1);
        dot = __builtin_fmaf(sk, ws[q], dot);
        float sn = __builtin_fmaf(c2, sk, -skm1);
        skm1 = sk; sk = sn;
      }
      float2 f01 = __half22float2(*(__half2*)&Y0.x);
      float2 fzg = __half22float2(*(__half2*)&Y0.y);
      acc0 = __builtin_fmaf(g1, f01.x, acc0);
      acc1 = __builtin_fmaf(g1, f01.y, acc1);
      accs += leaky(dot + fzg.x);
      v0 = v1; v1 = v2; v2 = v3; Y0 = Y1; Y1 = Y2;
    }
    // tail (<=3 iterations): registers already hold the remaining edges
    for (; k < bnd; k++) {
      uint2 Y2 = Y1;
      if (k + 2 < bnd) Y2 = yzg[(__float_as_int(v2.z) << 4) + r];
      float skm1 = 0.f, sk = v0.x, c2 = v0.y;
      float g1 = bgr, dot = 0.f;
#pragma unroll
      for (int q = 0; q < RDIM; q++) {
        g1  = __builtin_fmaf(sk, wg[q], g1);
        dot = __builtin_fmaf(sk, ws[q], dot);
        float sn = __builtin_fmaf(c2, sk, -skm1);
        skm1 = sk; sk = sn;
      }
      float2 f01 = __half22float2(*(__half2*)&Y0.x);
      float2 fzg = __half22float2(*(__half2*)&Y0.y);
      acc0 = __builtin_fmaf(g1, f01.x, acc0);
      acc1 = __builtin_fmaf(g1, f01.y, acc1);
      accs += leaky(dot + fzg.x);
      v0 = v1; v1 = v2; Y0 = Y1; Y1 = Y2;
    }
  }
  float id = 1.0f / fmaxf((float)(bnd - a), 1.0f);
  uint2 Yg = yzg[(n << 4) + r];
  float gt = __half22float2(*(__half2*)&Yg.y).y;
  float2* xr2 = (float2*)xr;
  float2 x = xr2[(n << 4) + r];
  x.x += acc0 * id * gt;
  x.y += acc1 * id * gt;
  xr2[(n << 4) + r] = x;                // in-place safe: (n,r) written only by this thread
  float s_new = xs[(n << 4) + r] + accs * id;
  xs[(n << 4) + r] = s_new;

  if (write_next) {
    // fused k_pre for next layer: cross-r via 16-wide shuffles (same sum order as k_pre)
    float wmxn[16], wsan[16], wgtn[16];
#pragma unroll
    for (int q = 0; q < 16; q++) wmxn[q] = Wmixn[r * 16 + q];
#pragma unroll
    for (int q = 0; q < 16; q++) wsan[q] = Ws1n[q * 16 + r];
#pragma unroll
    for (int q = 0; q < 16; q++) wgtn[q] = Wgaten[q * 16 + r];
    float y0 = 0.f, y1 = 0.f;
    float z = bs1n[r], gtn = bgaten[r];
#pragma unroll
    for (int j = 0; j < 16; j++) {
      float xj0 = __shfl(x.x, j, 16);
      float xj1 = __shfl(x.y, j, 16);
      float sj  = __shfl(s_new, j, 16);
      y0 += wmxn[j] * xj0;
      y1 += wmxn[j] * xj1;
      z  += wsan[j] * sj;
      gtn += wgtn[j] * sj;
    }
    gtn = 1.0f / (1.0f + __expf(-gtn));
    __half2 hA = __floats2half2_rn(y0, y1);
    __half2 hB = __floats2half2_rn(z, gtn);
    uint2 w2;
    w2.x = *(unsigned int*)&hA;
    w2.y = *(unsigned int*)&hB;
    yzg_out[(n << 4) + r] = w2;
  }
}

// ---------- final rotate-out + MLP (wave-uniform scalar weight loads) + binned graph sum ----------
__global__ void __launch_bounds__(128) k_final(
    int N, const float* __restrict__ xr, const float* __restrict__ xs,
    const float* __restrict__ cthn, const float* __restrict__ sthn,
    const int* __restrict__ batch,
    const float* __restrict__ W1, const float* __restrict__ b1,
    const float* __restrict__ W2, const float* __restrict__ b2,
    float* __restrict__ out) {
  __shared__ float obin[320 * 6];
  int t = threadIdx.x;
  int start = blockIdx.x * 128;
  int n = start + t;
  int b0 = batch[min(start, N - 1)];
  int span = batch[min(start + 127, N - 1)] - b0;
  bool useLds = (span < 320);
  if (useLds) for (int i = t; i < (span + 1) * 6; i += 128) obin[i] = 0.f;
  __syncthreads();

  float u[NC];
  bool act = (n < N);
  if (act) {
    float xc[48];
    const float4* xs4 = (const float4*)(xs + (size_t)n * NS);
#pragma unroll
    for (int j = 0; j < 4; j++) {
      float4 v = xs4[j];
      xc[4 * j + 0] = v.x; xc[4 * j + 1] = v.y; xc[4 * j + 2] = v.z; xc[4 * j + 3] = v.w;
    }
    float c = cthn[n], s = sthn[n];
    const float4* xr4 = (const float4*)(xr + (size_t)n * 32);
#pragma unroll
    for (int j = 0; j < 8; j++) {
      float4 v = xr4[j];
      xc[16 + 4 * j + 0] = c * v.x - s * v.y;
      xc[16 + 4 * j + 1] = s * v.x + c * v.y;
      xc[16 + 4 * j + 2] = c * v.z - s * v.w;
      xc[16 + 4 * j + 3] = s * v.z + c * v.w;
    }
#pragma unroll
    for (int q = 0; q < NC; q++) u[q] = b2[q];
    for (int h = 0; h < H1; h += 4) {
      float a0 = b1[h + 0], a1 = b1[h + 1], a2 = b1[h + 2], a3 = b1[h + 3];
#pragma unroll
      for (int q = 0; q < 48; q++) {
        // uniform address (h,q uniform) -> s_load_dwordx4, cached in K$/L1
        float4 w = *(const float4*)(W1 + (size_t)q * H1 + h);
        float x = xc[q];
        a0 = __builtin_fmaf(x, w.x, a0);
        a1 = __builtin_fmaf(x, w.y, a1);
        a2 = __builtin_fmaf(x, w.z, a2);
        a3 = __builtin_fmaf(x, w.w, a3);
      }
      a0 = leaky(a0); a1 = leaky(a1); a2 = leaky(a2); a3 = leaky(a3);
#pragma unroll
      for (int q = 0; q < NC; q++)
        u[q] += a0 * W2[(h + 0) * 6 + q] + a1 * W2[(h + 1) * 6 + q]
              + a2 * W2[(h + 2) * 6 + q] + a3 * W2[(h + 3) * 6 + q];
    }
  }
  if (useLds) {
    if (act) {
      int rb = batch[n] - b0;
#pragma unroll
      for (int q = 0; q < NC; q++) atomicAdd(&obin[rb * 6 + q], u[q]);
    }
    __syncthreads();
    for (int i = t; i < (span + 1) * 6; i += 128) atomicAdd(&out[b0 * 6 + i], obin[i]);
  } else if (act) {
    int b = batch[n];
#pragma unroll
    for (int q = 0; q < NC; q++) atomicAdd(&out[b * 6 + q], u[q]);
  }
}

extern "C" void kernel_launch(void* const* d_in, const int* in_sizes, int n_in,
                              void* d_out, int out_size, void* d_ws, size_t ws_size,
                              hipStream_t stream) {
  const float* pos   = (const float*)d_in[0];
  const float* Wer   = (const float*)d_in[1];
  const float* wse   = (const float*)d_in[2];
  const float* bse   = (const float*)d_in[3];
  const float* Wg    = (const float*)d_in[4];
  const float* bg    = (const float*)d_in[5];
  const float* Wmix  = (const float*)d_in[6];
  const float* Wgate = (const float*)d_in[7];
  const float* bgate = (const float*)d_in[8];
  const float* Ws1   = (const float*)d_in[9];
  const float* bs1   = (const float*)d_in[10];
  const float* W1    = (const float*)d_in[11];
  const float* b1    = (const float*)d_in[12];
  const float* W2    = (const float*)d_in[13];
  const float* b2    = (const float*)d_in[14];
  const int*   ei    = (const int*)d_in[15];
  const int*   batch = (const int*)d_in[16];
  float* out = (float*)d_out;

  int N = in_sizes[0] / 2;
  int E = in_sizes[15] / 2;
  int G = out_size / NC;

  // ---- workspace layout (~75 MB for N=100k, E=1.6M) ----
  float* W = (float*)d_ws;
  size_t o = 0;
  float* gsum   = W + o; o += (size_t)2 * G;
  float* gcnt   = W + o; o += (size_t)G;
  int*   cnt    = (int*)(W + o); o += (size_t)N;
  int*   cursor = (int*)(W + o); o += (size_t)N;
  int*   dhist  = (int*)(W + o); o += (size_t)DBINS;
  size_t zero_bytes = o * 4;
  o = (o + 3) & ~(size_t)3;
  float* posc   = W + o; o += (size_t)2 * N;
  float* cthn   = W + o; o += (size_t)N;
  float* sthn   = W + o; o += (size_t)N;
  int*   off    = (int*)(W + o); o += (size_t)N + 1; o = (o + 3) & ~(size_t)3;
  int*   bsum   = (int*)(W + o); o += (size_t)1024;
  int*   dcur   = (int*)(W + o); o += (size_t)DBINS;
  int*   perm   = (int*)(W + o); o += (size_t)N; o = (o + 3) & ~(size_t)3;
  float4* csr   = (float4*)(W + o); o += (size_t)4 * E;
  uint2* yzgA   = (uint2*)(W + o); o += (size_t)32 * N;
  uint2* yzgB   = (uint2*)(W + o); o += (size_t)32 * N;
  float* xr     = W + o; o += (size_t)N * 32;
  float* xs     = W + o; o += (size_t)N * 16;
  (void)ws_size;

  hipMemsetAsync(d_ws, 0, zero_bytes, stream);
  hipMemsetAsync(d_out, 0, (size_t)out_size * 4, stream);

  int nbN  = (N + 255) / 256;
  int nbE  = (E + 255) / 256;
  int nbN16 = ((size_t)N * 16 + 255) / 256;
  int nbS  = (N + 1023) / 1024;
  int nbS3 = (N + 1 + 1023) / 1024;
  int nbF  = (N + 127) / 128;

  k_gsum_count<<<nbE, 256, 0, stream>>>(pos, batch, N, gsum, gcnt, ei, E, cnt);
  k_center_dhist_scan1<<<nbS, 1024, 0, stream>>>(pos, batch, N, gsum, gcnt,
                                                 posc, cthn, sthn, cnt, dhist, off, bsum);
  k_dscan_scan2<<<1, 1024, 0, stream>>>(dhist, dcur, bsum, nbS);
  k_dfill_scan3<<<nbS3, 1024, 0, stream>>>(off, bsum, N, E, cnt, dcur, perm, cursor);
  k_build<<<nbE, 256, 0, stream>>>(posc, ei, E, cursor, csr);
  k_init16<<<nbN16, 256, 0, stream>>>(N, off, csr, posc, Wer, wse, bse,
                                      Wmix, Ws1, bs1, Wgate, bgate,
                                      xr, xs, yzgA);

  // layer 0: read A, write B (fused pre for layer 1)
  k_layer<<<nbN16, 256, 0, stream>>>(N, off, csr, yzgA, perm,
                                     Wg, bg, Ws1, xr, xs,
                                     1, yzgB,
                                     Wmix + 256, Ws1 + 512, bs1 + 16, Wgate + 256, bgate + 16);
  // layer 1: read B, write A (fused pre for layer 2)
  k_layer<<<nbN16, 256, 0, stream>>>(N, off, csr, yzgB, perm,
                                     Wg + 256, bg + 16, Ws1 + 512, xr, xs,
                                     1, yzgA,
                                     Wmix + 512, Ws1 + 1024, bs1 + 32, Wgate + 512, bgate + 32);
  // layer 2: read A, no next
  k_layer<<<nbN16, 256, 0, stream>>>(N, off, csr, yzgA, perm,
                                     Wg + 512, bg + 32, Ws1 + 1024, xr, xs,
                                     0, yzgB,
                                     Wmix, Ws1, bs1, Wgate, bgate);

  k_final<<<nbF, 128, 0, stream>>>(N, xr, xs, cthn, sthn, batch, W1, b1, W2, b2, out);
}